// Round 1
// baseline (1257.074 us; speedup 1.0000x reference)
//
#include <hip/hip_runtime.h>
#include <hip/hip_bf16.h>

typedef __attribute__((ext_vector_type(4))) float f32x4;
typedef __attribute__((ext_vector_type(8))) short s16x8;
typedef __attribute__((ext_vector_type(4))) unsigned short u16x4;
typedef __attribute__((ext_vector_type(8))) unsigned short u16x8;
typedef __attribute__((ext_vector_type(4))) int i32x4;

#define NB 64
#define NS 256
#define ND 2048
#define NH 16
#define NHD 128
#define NM (NB*NS)   // 16384

__device__ __forceinline__ unsigned short f2bf(float f){
  unsigned int u = __float_as_uint(f);
  u += 0x7fffu + ((u >> 16) & 1u);
  return (unsigned short)(u >> 16);
}

__device__ __forceinline__ void gload16(const void* g, void* l){
  __builtin_amdgcn_global_load_lds(
    (const __attribute__((address_space(1))) unsigned int*)g,
    (__attribute__((address_space(3))) unsigned int*)l, 16, 0, 0);
}

// ---------------- fp32 -> bf16 conversion (weights) ----------------
__global__ __launch_bounds__(256) void wconv(const float* __restrict__ s,
                                             unsigned short* __restrict__ d, int n8){
  int i = blockIdx.x*256 + threadIdx.x;
  if (i >= n8) return;
  f32x4 a = *(const f32x4*)(s + (size_t)i*8);
  f32x4 b = *(const f32x4*)(s + (size_t)i*8 + 4);
  u16x8 u;
  #pragma unroll
  for (int r=0;r<4;r++){ u[r]=f2bf(a[r]); u[4+r]=f2bf(b[r]); }
  *(u16x8*)(d + (size_t)i*8) = u;
}

// ---------------- shared GEMM body: C = A @ W^T + bias ----------------
// AMODE 0: A fp32 (reg-staged convert); AMODE 1: A bf16 (global_load_lds)
// OUTMODE 0: bf16 [b][h][s][hd]; OUTMODE 1: bf16 V^T [b][h][d][s]; OUTMODE 2: fp32 [m][n]
template<int AMODE, int OUTMODE>
__device__ __forceinline__ void gemm_body(
    const void* __restrict__ Aany, const unsigned short* __restrict__ Bw,
    const float* __restrict__ bias, void* __restrict__ Out)
{
  __shared__ unsigned short Abuf[128*64];
  __shared__ unsigned short Bbuf[128*64];
  char* AbufB = (char*)Abuf; char* BbufB = (char*)Bbuf;
  const int tid  = threadIdx.x;
  const int lane = tid & 63, wid = tid >> 6;
  const int g = lane >> 4, l15 = lane & 15;
  const int wm = wid >> 1, wn = wid & 1;
  const int mt = blockIdx.x >> 4, nt = blockIdx.x & 15;
  const int m0 = mt*128, n0 = nt*128;
  const int srow = tid >> 3, slot = tid & 7;

  f32x4 acc[4][4];
  #pragma unroll
  for (int i=0;i<4;i++)
    #pragma unroll
    for (int j=0;j<4;j++) acc[i][j] = f32x4{0.f,0.f,0.f,0.f};

  for (int kt = 0; kt < ND; kt += 64) {
    // stage B tile (bf16 weights) via global_load_lds, source pre-swizzled
    #pragma unroll
    for (int c=0;c<4;c++){
      int row = c*32 + srow;
      int ss  = slot ^ (row & 7);
      gload16(Bw + (size_t)(n0+row)*ND + kt + ss*8, BbufB + c*4096 + tid*16);
    }
    if (AMODE == 0){
      const float* Af = (const float*)Aany;
      #pragma unroll
      for (int c=0;c<4;c++){
        int row = c*32 + srow;
        const float* src = Af + (size_t)(m0+row)*ND + kt + slot*8;
        f32x4 x = *(const f32x4*)src;
        f32x4 y = *(const f32x4*)(src+4);
        u16x8 u;
        #pragma unroll
        for (int r=0;r<4;r++){ u[r]=f2bf(x[r]); u[4+r]=f2bf(y[r]); }
        *(u16x8*)(AbufB + row*128 + ((slot ^ (row&7))*16)) = u;
      }
    } else {
      const unsigned short* Ab = (const unsigned short*)Aany;
      #pragma unroll
      for (int c=0;c<4;c++){
        int row = c*32 + srow;
        int ss  = slot ^ (row & 7);
        gload16(Ab + (size_t)(m0+row)*ND + kt + ss*8, AbufB + c*4096 + tid*16);
      }
    }
    __syncthreads();
    #pragma unroll
    for (int kk=0;kk<2;kk++){
      s16x8 av[4], bv[4];
      #pragma unroll
      for (int i=0;i<4;i++){
        int r = wm*64 + i*16 + l15;
        av[i] = *(const s16x8*)(AbufB + r*128 + (((kk*4+g) ^ (r&7))*16));
      }
      #pragma unroll
      for (int j=0;j<4;j++){
        int r = wn*64 + j*16 + l15;
        bv[j] = *(const s16x8*)(BbufB + r*128 + (((kk*4+g) ^ (r&7))*16));
      }
      #pragma unroll
      for (int i=0;i<4;i++)
        #pragma unroll
        for (int j=0;j<4;j++)
          acc[i][j] = __builtin_amdgcn_mfma_f32_16x16x32_bf16(av[i], bv[j], acc[i][j], 0,0,0);
    }
    __syncthreads();
  }
  // epilogue
  #pragma unroll
  for (int j=0;j<4;j++){
    int n = n0 + wn*64 + j*16 + l15;
    float bj = bias[n];
    #pragma unroll
    for (int i=0;i<4;i++){
      int mb = m0 + wm*64 + i*16 + g*4;
      if (OUTMODE == 2){
        float* O = (float*)Out;
        #pragma unroll
        for (int r=0;r<4;r++) O[(size_t)(mb+r)*ND + n] = acc[i][j][r] + bj;
      } else if (OUTMODE == 0){
        unsigned short* O = (unsigned short*)Out;
        int bb = mb >> 8, h = n >> 7, d = n & 127, s0 = mb & 255;
        #pragma unroll
        for (int r=0;r<4;r++)
          O[(((size_t)bb*NH + h)*NS + s0 + r)*NHD + d] = f2bf(acc[i][j][r] + bj);
      } else {
        unsigned short* O = (unsigned short*)Out;
        int bb = mb >> 8, h = n >> 7, d = n & 127, s0 = mb & 255;
        u16x4 u;
        #pragma unroll
        for (int r=0;r<4;r++) u[r] = f2bf(acc[i][j][r] + bj);
        *(u16x4*)(O + (((size_t)bb*NH + h)*NHD + d)*NS + s0) = u;
      }
    }
  }
}

__global__ __launch_bounds__(256) void proj_kernel(
  const float* __restrict__ q, const float* __restrict__ k, const float* __restrict__ v,
  const unsigned short* __restrict__ Wqb, const unsigned short* __restrict__ Wkb,
  const unsigned short* __restrict__ Wvb,
  const float* __restrict__ bq, const float* __restrict__ bk, const float* __restrict__ bv,
  unsigned short* __restrict__ Qh, unsigned short* __restrict__ Kh,
  unsigned short* __restrict__ VT)
{
  int z = blockIdx.y;
  if (z == 0)      gemm_body<0,0>(q, Wqb, bq, Qh);
  else if (z == 1) gemm_body<0,0>(k, Wkb, bk, Kh);
  else             gemm_body<0,1>(v, Wvb, bv, VT);
}

__global__ __launch_bounds__(256) void oproj_kernel(
  const unsigned short* __restrict__ AO, const unsigned short* __restrict__ Wob,
  const float* __restrict__ bo, float* __restrict__ Out)
{
  gemm_body<1,2>(AO, Wob, bo, Out);
}

// ---------------- attention: scores + softmax -> P (bf16) ----------------
// swapped operands: ST = K * Q^T so each lane owns one q column; C-frag rows (k)
// are contiguous -> P[q][k] written as u16x4.
__global__ __launch_bounds__(256) void attn_scores_kernel(
  const unsigned short* __restrict__ Qh, const unsigned short* __restrict__ Kh,
  const int* __restrict__ mask, const float* __restrict__ bias_table,
  unsigned short* __restrict__ P)
{
  const int bh = blockIdx.x >> 2, qt = blockIdx.x & 3;
  const int b = bh >> 4, h = bh & 15;
  const int lane = threadIdx.x & 63, wid = threadIdx.x >> 6;
  const int g = lane >> 4, l15 = lane & 15;
  const int q = qt*64 + wid*16 + l15;

  const unsigned short* Qrow = Qh + ((size_t)bh*NS + q)*NHD;
  s16x8 bq[4];
  #pragma unroll
  for (int kk=0;kk<4;kk++) bq[kk] = *(const s16x8*)(Qrow + kk*32 + g*8);

  const unsigned short* Kb = Kh + (size_t)bh*NS*NHD;
  f32x4 c[16];
  #pragma unroll
  for (int kb=0;kb<16;kb++){
    c[kb] = f32x4{0.f,0.f,0.f,0.f};
    const unsigned short* Kr = Kb + (size_t)(kb*16 + l15)*NHD;
    #pragma unroll
    for (int kk=0;kk<4;kk++){
      s16x8 a = *(const s16x8*)(Kr + kk*32 + g*8);
      c[kb] = __builtin_amdgcn_mfma_f32_16x16x32_bf16(a, bq[kk], c[kb], 0,0,0);
    }
  }

  const float scale = 0.08838834764831845f; // 1/sqrt(128)
  const float* brow = bias_table + ((size_t)h*NS + q)*NS;
  const int*   mrow = mask + b*NS;
  float mx = -3.0e38f;
  #pragma unroll
  for (int kb=0;kb<16;kb++){
    f32x4 b4 = *(const f32x4*)(brow + kb*16 + g*4);
    i32x4 m4 = *(const i32x4*)(mrow + kb*16 + g*4);
    #pragma unroll
    for (int r=0;r<4;r++){
      float val = (m4[r] != 0) ? (c[kb][r]*scale + b4[r]) : -3.0e38f;
      c[kb][r] = val;
      mx = fmaxf(mx, val);
    }
  }
  mx = fmaxf(mx, __shfl_xor(mx, 16));
  mx = fmaxf(mx, __shfl_xor(mx, 32));
  float sum = 0.f;
  #pragma unroll
  for (int kb=0;kb<16;kb++)
    #pragma unroll
    for (int r=0;r<4;r++){
      float p = __expf(c[kb][r] - mx);
      c[kb][r] = p; sum += p;
    }
  sum += __shfl_xor(sum, 16);
  sum += __shfl_xor(sum, 32);
  float inv = 1.f / sum;

  unsigned short* Prow = P + ((size_t)bh*NS + q)*NS;
  #pragma unroll
  for (int kb=0;kb<16;kb++){
    u16x4 u;
    #pragma unroll
    for (int r=0;r<4;r++) u[r] = f2bf(c[kb][r] * inv);
    *(u16x4*)(Prow + kb*16 + g*4) = u;
  }
}

// ---------------- attention: O^T = V^T * P^T  -> AO (B,S,D) bf16 ----------------
__global__ __launch_bounds__(256) void attn_pv_kernel(
  const unsigned short* __restrict__ P, const unsigned short* __restrict__ VT,
  unsigned short* __restrict__ AO)
{
  const int bh = blockIdx.x, b = bh >> 4, h = bh & 15;
  const int lane = threadIdx.x & 63, wid = threadIdx.x >> 6;
  const int g = lane >> 4, l15 = lane & 15;
  const unsigned short* vt = VT + (size_t)bh*NHD*NS;
  const unsigned short* pp = P  + (size_t)bh*NS*NS;

  f32x4 acc[2][16];
  #pragma unroll
  for (int db=0;db<2;db++)
    #pragma unroll
    for (int qb=0;qb<16;qb++) acc[db][qb] = f32x4{0.f,0.f,0.f,0.f};

  for (int kk=0;kk<8;kk++){
    s16x8 a[2];
    #pragma unroll
    for (int db=0;db<2;db++)
      a[db] = *(const s16x8*)(vt + (size_t)(wid*32 + db*16 + l15)*NS + kk*32 + g*8);
    #pragma unroll
    for (int qb=0;qb<16;qb++){
      s16x8 bf = *(const s16x8*)(pp + (size_t)(qb*16 + l15)*NS + kk*32 + g*8);
      #pragma unroll
      for (int db=0;db<2;db++)
        acc[db][qb] = __builtin_amdgcn_mfma_f32_16x16x32_bf16(a[db], bf, acc[db][qb], 0,0,0);
    }
  }
  #pragma unroll
  for (int qb=0;qb<16;qb++){
    int qq = qb*16 + l15;
    #pragma unroll
    for (int db=0;db<2;db++){
      u16x4 u;
      #pragma unroll
      for (int r=0;r<4;r++) u[r] = f2bf(acc[db][qb][r]);
      *(u16x4*)(AO + ((size_t)b*NS + qq)*ND + h*NHD + wid*32 + db*16 + g*4) = u;
    }
  }
}

extern "C" void kernel_launch(void* const* d_in, const int* in_sizes, int n_in,
                              void* d_out, int out_size, void* d_ws, size_t ws_size,
                              hipStream_t stream)
{
  const float* q  = (const float*)d_in[0];
  const float* k  = (const float*)d_in[1];
  const float* v  = (const float*)d_in[2];
  const int* mask = (const int*)d_in[3];
  const float* Wq = (const float*)d_in[4];
  const float* bq = (const float*)d_in[5];
  const float* Wk = (const float*)d_in[6];
  const float* bk = (const float*)d_in[7];
  const float* Wv = (const float*)d_in[8];
  const float* bv = (const float*)d_in[9];
  const float* Wo = (const float*)d_in[10];
  const float* bo = (const float*)d_in[11];
  const float* bias_table = (const float*)d_in[12];

  char* ws = (char*)d_ws;
  unsigned short* Wqb = (unsigned short*)(ws + 0);
  unsigned short* Wkb = (unsigned short*)(ws + 8388608);
  unsigned short* Wvb = (unsigned short*)(ws + 16777216);
  unsigned short* Wob = (unsigned short*)(ws + 25165824);
  unsigned short* Qh  = (unsigned short*)(ws + 33554432);   // 67,108,864 B
  unsigned short* Kh  = (unsigned short*)(ws + 100663296);  // 67,108,864 B
  unsigned short* VT  = (unsigned short*)(ws + 167772160);  // 67,108,864 B
  unsigned short* Pb  = (unsigned short*)(ws + 234881024);  // 33,554,432 B  (total 256 MiB)
  unsigned short* AO  = Qh;  // alias: Qh is dead after attn_scores_kernel

  wconv<<<2048,256,0,stream>>>(Wq, Wqb, 524288);
  wconv<<<2048,256,0,stream>>>(Wk, Wkb, 524288);
  wconv<<<2048,256,0,stream>>>(Wv, Wvb, 524288);
  wconv<<<2048,256,0,stream>>>(Wo, Wob, 524288);

  proj_kernel<<<dim3(2048,3),256,0,stream>>>(q,k,v,Wqb,Wkb,Wvb,bq,bk,bv,Qh,Kh,VT);
  attn_scores_kernel<<<4096,256,0,stream>>>(Qh,Kh,mask,bias_table,Pb);
  attn_pv_kernel<<<1024,256,0,stream>>>(Pb,VT,AO);
  oproj_kernel<<<2048,256,0,stream>>>(AO,Wob,bo,(float*)d_out);
}

// Round 3
// 1162.033 us; speedup vs baseline: 1.0818x; 1.0818x over previous
//
#include <hip/hip_runtime.h>
#include <hip/hip_bf16.h>

typedef __attribute__((ext_vector_type(4))) float f32x4;
typedef __attribute__((ext_vector_type(8))) short s16x8;
typedef __attribute__((ext_vector_type(4))) unsigned short u16x4;
typedef __attribute__((ext_vector_type(8))) unsigned short u16x8;
typedef __attribute__((ext_vector_type(4))) int i32x4;

#define NB 64
#define NS 256
#define ND 2048
#define NH 16
#define NHD 128
#define NM (NB*NS)   // 16384

__device__ __forceinline__ unsigned short f2bf(float f){
  unsigned int u = __float_as_uint(f);
  u += 0x7fffu + ((u >> 16) & 1u);
  return (unsigned short)(u >> 16);
}

__device__ __forceinline__ void gload16(const void* g, void* l){
  __builtin_amdgcn_global_load_lds(
    (const __attribute__((address_space(1))) unsigned int*)g,
    (__attribute__((address_space(3))) unsigned int*)l, 16, 0, 0);
}

// ---------------- fp32 -> bf16 conversion (weights & activations) ----------------
__global__ __launch_bounds__(256) void wconv(const float* __restrict__ s,
                                             unsigned short* __restrict__ d, int n8){
  int i = blockIdx.x*256 + threadIdx.x;
  if (i >= n8) return;
  f32x4 a = *(const f32x4*)(s + (size_t)i*8);
  f32x4 b = *(const f32x4*)(s + (size_t)i*8 + 4);
  u16x8 u;
  #pragma unroll
  for (int r=0;r<4;r++){ u[r]=f2bf(a[r]); u[4+r]=f2bf(b[r]); }
  *(u16x8*)(d + (size_t)i*8) = u;
}

// ---------------- GEMM: C = A(bf16) @ W^T(bf16) + bias ----------------
// m97 structure: 128x128 tile, BK=64, global_load_lds w16 for A and B,
// XOR-swizzled LDS (pre-swizzled global source, swizzled ds_read).
// OUTMODE 0: bf16 [b][h][s][hd]; OUTMODE 1: bf16 V^T [b][h][d][s]; OUTMODE 2: fp32 [m][n]
template<int OUTMODE>
__global__ __launch_bounds__(256) void gemm_bf16(
    const unsigned short* __restrict__ A, const unsigned short* __restrict__ Bw,
    const float* __restrict__ bias, void* __restrict__ Out, int m_base)
{
  __shared__ unsigned short Abuf[128*64];
  __shared__ unsigned short Bbuf[128*64];
  char* AbufB = (char*)Abuf; char* BbufB = (char*)Bbuf;
  const int tid  = threadIdx.x;
  const int lane = tid & 63, wid = tid >> 6;
  const int g = lane >> 4, l15 = lane & 15;
  const int wm = wid >> 1, wn = wid & 1;
  const int mt = blockIdx.x >> 4, nt = blockIdx.x & 15;
  const int mloc = mt*128, n0 = nt*128;
  const int srow = tid >> 3, slot = tid & 7;

  f32x4 acc[4][4];
  #pragma unroll
  for (int i=0;i<4;i++)
    #pragma unroll
    for (int j=0;j<4;j++) acc[i][j] = f32x4{0.f,0.f,0.f,0.f};

  for (int kt = 0; kt < ND; kt += 64) {
    #pragma unroll
    for (int c=0;c<4;c++){
      int row = c*32 + srow;
      int ss  = slot ^ (row & 7);
      gload16(Bw + (size_t)(n0+row)*ND + kt + ss*8, BbufB + c*4096 + tid*16);
      gload16(A  + (size_t)(mloc+row)*ND + kt + ss*8, AbufB + c*4096 + tid*16);
    }
    __syncthreads();
    #pragma unroll
    for (int kk=0;kk<2;kk++){
      s16x8 av[4], bv[4];
      #pragma unroll
      for (int i=0;i<4;i++){
        int r = wm*64 + i*16 + l15;
        av[i] = *(const s16x8*)(AbufB + r*128 + (((kk*4+g) ^ (r&7))*16));
      }
      #pragma unroll
      for (int j=0;j<4;j++){
        int r = wn*64 + j*16 + l15;
        bv[j] = *(const s16x8*)(BbufB + r*128 + (((kk*4+g) ^ (r&7))*16));
      }
      #pragma unroll
      for (int i=0;i<4;i++)
        #pragma unroll
        for (int j=0;j<4;j++)
          acc[i][j] = __builtin_amdgcn_mfma_f32_16x16x32_bf16(av[i], bv[j], acc[i][j], 0,0,0);
    }
    __syncthreads();
  }
  // epilogue
  #pragma unroll
  for (int j=0;j<4;j++){
    int n = n0 + wn*64 + j*16 + l15;
    float bj = bias[n];
    #pragma unroll
    for (int i=0;i<4;i++){
      int mb = m_base + mloc + wm*64 + i*16 + g*4;
      if (OUTMODE == 2){
        float* O = (float*)Out;
        #pragma unroll
        for (int r=0;r<4;r++) O[(size_t)(mb+r)*ND + n] = acc[i][j][r] + bj;
      } else if (OUTMODE == 0){
        unsigned short* O = (unsigned short*)Out;
        int bb = mb >> 8, h = n >> 7, d = n & 127, s0 = mb & 255;
        #pragma unroll
        for (int r=0;r<4;r++)
          O[(((size_t)bb*NH + h)*NS + s0 + r)*NHD + d] = f2bf(acc[i][j][r] + bj);
      } else {
        unsigned short* O = (unsigned short*)Out;
        int bb = mb >> 8, h = n >> 7, d = n & 127, s0 = mb & 255;
        u16x4 u;
        #pragma unroll
        for (int r=0;r<4;r++) u[r] = f2bf(acc[i][j][r] + bj);
        *(u16x4*)(O + (((size_t)bb*NH + h)*NHD + d)*NS + s0) = u;
      }
    }
  }
}

// ---------------- attention: scores + softmax -> P (bf16) ----------------
__global__ __launch_bounds__(256) void attn_scores_kernel(
  const unsigned short* __restrict__ Qh, const unsigned short* __restrict__ Kh,
  const int* __restrict__ mask, const float* __restrict__ bias_table,
  unsigned short* __restrict__ P)
{
  const int bh = blockIdx.x >> 2, qt = blockIdx.x & 3;
  const int b = bh >> 4, h = bh & 15;
  const int lane = threadIdx.x & 63, wid = threadIdx.x >> 6;
  const int g = lane >> 4, l15 = lane & 15;
  const int q = qt*64 + wid*16 + l15;

  const unsigned short* Qrow = Qh + ((size_t)bh*NS + q)*NHD;
  s16x8 bq[4];
  #pragma unroll
  for (int kk=0;kk<4;kk++) bq[kk] = *(const s16x8*)(Qrow + kk*32 + g*8);

  const unsigned short* Kb = Kh + (size_t)bh*NS*NHD;
  f32x4 c[16];
  #pragma unroll
  for (int kb=0;kb<16;kb++){
    c[kb] = f32x4{0.f,0.f,0.f,0.f};
    const unsigned short* Kr = Kb + (size_t)(kb*16 + l15)*NHD;
    #pragma unroll
    for (int kk=0;kk<4;kk++){
      s16x8 a = *(const s16x8*)(Kr + kk*32 + g*8);
      c[kb] = __builtin_amdgcn_mfma_f32_16x16x32_bf16(a, bq[kk], c[kb], 0,0,0);
    }
  }

  const float scale = 0.08838834764831845f; // 1/sqrt(128)
  const float* brow = bias_table + ((size_t)h*NS + q)*NS;
  const int*   mrow = mask + b*NS;
  float mx = -3.0e38f;
  #pragma unroll
  for (int kb=0;kb<16;kb++){
    f32x4 b4 = *(const f32x4*)(brow + kb*16 + g*4);
    i32x4 m4 = *(const i32x4*)(mrow + kb*16 + g*4);
    #pragma unroll
    for (int r=0;r<4;r++){
      float val = (m4[r] != 0) ? (c[kb][r]*scale + b4[r]) : -3.0e38f;
      c[kb][r] = val;
      mx = fmaxf(mx, val);
    }
  }
  mx = fmaxf(mx, __shfl_xor(mx, 16));
  mx = fmaxf(mx, __shfl_xor(mx, 32));
  float sum = 0.f;
  #pragma unroll
  for (int kb=0;kb<16;kb++)
    #pragma unroll
    for (int r=0;r<4;r++){
      float p = __expf(c[kb][r] - mx);
      c[kb][r] = p; sum += p;
    }
  sum += __shfl_xor(sum, 16);
  sum += __shfl_xor(sum, 32);
  float inv = 1.f / sum;

  unsigned short* Prow = P + ((size_t)bh*NS + q)*NS;
  #pragma unroll
  for (int kb=0;kb<16;kb++){
    u16x4 u;
    #pragma unroll
    for (int r=0;r<4;r++) u[r] = f2bf(c[kb][r] * inv);
    *(u16x4*)(Prow + kb*16 + g*4) = u;
  }
}

// ---------------- attention: O^T = V^T * P^T -> AO (B,S,D) bf16 ----------------
__global__ __launch_bounds__(256) void attn_pv_kernel(
  const unsigned short* __restrict__ P, const unsigned short* __restrict__ VT,
  unsigned short* __restrict__ AO)
{
  const int bh = blockIdx.x, b = bh >> 4, h = bh & 15;
  const int lane = threadIdx.x & 63, wid = threadIdx.x >> 6;
  const int g = lane >> 4, l15 = lane & 15;
  const unsigned short* vt = VT + (size_t)bh*NHD*NS;
  const unsigned short* pp = P  + (size_t)bh*NS*NS;

  f32x4 acc[2][16];
  #pragma unroll
  for (int db=0;db<2;db++)
    #pragma unroll
    for (int qb=0;qb<16;qb++) acc[db][qb] = f32x4{0.f,0.f,0.f,0.f};

  for (int kk=0;kk<8;kk++){
    s16x8 a[2];
    #pragma unroll
    for (int db=0;db<2;db++)
      a[db] = *(const s16x8*)(vt + (size_t)(wid*32 + db*16 + l15)*NS + kk*32 + g*8);
    #pragma unroll
    for (int qb=0;qb<16;qb++){
      s16x8 bf = *(const s16x8*)(pp + (size_t)(qb*16 + l15)*NS + kk*32 + g*8);
      #pragma unroll
      for (int db=0;db<2;db++)
        acc[db][qb] = __builtin_amdgcn_mfma_f32_16x16x32_bf16(a[db], bf, acc[db][qb], 0,0,0);
    }
  }
  #pragma unroll
  for (int qb=0;qb<16;qb++){
    int qq = qb*16 + l15;
    #pragma unroll
    for (int db=0;db<2;db++){
      u16x4 u;
      #pragma unroll
      for (int r=0;r<4;r++) u[r] = f2bf(acc[db][qb][r]);
      *(u16x4*)(AO + ((size_t)b*NS + qq)*ND + h*NHD + wid*32 + db*16 + g*4) = u;
    }
  }
}

extern "C" void kernel_launch(void* const* d_in, const int* in_sizes, int n_in,
                              void* d_out, int out_size, void* d_ws, size_t ws_size,
                              hipStream_t stream)
{
  const float* q  = (const float*)d_in[0];
  const float* k  = (const float*)d_in[1];
  const float* v  = (const float*)d_in[2];
  const int* mask = (const int*)d_in[3];
  const float* Wq = (const float*)d_in[4];
  const float* bq = (const float*)d_in[5];
  const float* Wk = (const float*)d_in[6];
  const float* bk = (const float*)d_in[7];
  const float* Wv = (const float*)d_in[8];
  const float* bv = (const float*)d_in[9];
  const float* Wo = (const float*)d_in[10];
  const float* bo = (const float*)d_in[11];
  const float* bias_table = (const float*)d_in[12];

  // workspace layout, max byte touched = 352 MiB (369,098,752 B — exactly the
  // footprint round 1 successfully used):
  //   Wob [0,8M)      output-proj weight bf16
  //   wb  [8M,16M)    shared QKV weight bf16 (reused per projection)
  //   tmp [16M,32M)   quarter-M activation bf16 chunk (4096x2048)
  //   Qh  [32M,96M)   Kh [96M,160M)   VT [160M,224M)
  //   P   [224M,352M) full 128 MiB — disjoint from live Qh/Kh/VT
  //   AO aliases Qh (dead after attn_scores); disjoint from P and VT.
  char* ws = (char*)d_ws;
  unsigned short* Wob = (unsigned short*)(ws + 0);
  unsigned short* wb  = (unsigned short*)(ws + 8388608);
  unsigned short* tmp = (unsigned short*)(ws + 16777216);
  unsigned short* Qh  = (unsigned short*)(ws + 33554432);
  unsigned short* Kh  = (unsigned short*)(ws + 100663296);
  unsigned short* VT  = (unsigned short*)(ws + 167772160);
  unsigned short* Pb  = (unsigned short*)(ws + 234881024);
  unsigned short* AO  = Qh;    // alias: Qh dead after attn_scores

  wconv<<<2048,256,0,stream>>>(Wo, Wob, 524288);

  const float* acts[3]  = {q, k, v};
  const float* wgt[3]   = {Wq, Wk, Wv};
  const float* bia[3]   = {bq, bk, bv};
  unsigned short* outs[3] = {Qh, Kh, VT};

  for (int x = 0; x < 3; ++x) {
    wconv<<<2048,256,0,stream>>>(wgt[x], wb, 524288);
    for (int qtr = 0; qtr < 4; ++qtr) {
      const float* src = acts[x] + (size_t)qtr*4096*ND;
      wconv<<<4096,256,0,stream>>>(src, tmp, 1048576);
      if (x < 2)
        gemm_bf16<0><<<512,256,0,stream>>>(tmp, wb, bia[x], outs[x], qtr*4096);
      else
        gemm_bf16<1><<<512,256,0,stream>>>(tmp, wb, bia[x], outs[x], qtr*4096);
    }
  }

  attn_scores_kernel<<<4096,256,0,stream>>>(Qh,Kh,mask,bias_table,Pb);
  attn_pv_kernel<<<1024,256,0,stream>>>(Pb,VT,AO);
  gemm_bf16<2><<<2048,256,0,stream>>>(AO,Wob,bo,(float*)d_out,0);
}

// Round 4
// 988.819 us; speedup vs baseline: 1.2713x; 1.1752x over previous
//
#include <hip/hip_runtime.h>
#include <hip/hip_bf16.h>

typedef __attribute__((ext_vector_type(4))) float f32x4;
typedef __attribute__((ext_vector_type(8))) short s16x8;
typedef __attribute__((ext_vector_type(4))) unsigned short u16x4;
typedef __attribute__((ext_vector_type(8))) unsigned short u16x8;
typedef __attribute__((ext_vector_type(4))) int i32x4;

#define NB 64
#define NS 256
#define ND 2048
#define NH 16
#define NHD 128

__device__ __forceinline__ unsigned short f2bf(float f){
  unsigned int u = __float_as_uint(f);
  u += 0x7fffu + ((u >> 16) & 1u);
  return (unsigned short)(u >> 16);
}

__device__ __forceinline__ void gload16(const void* g, void* l){
  __builtin_amdgcn_global_load_lds(
    (const __attribute__((address_space(1))) unsigned int*)g,
    (__attribute__((address_space(3))) unsigned int*)l, 16, 0, 0);
}

// ---------------- fp32 -> bf16 conversion ----------------
__global__ __launch_bounds__(256) void wconv(const float* __restrict__ s,
                                             unsigned short* __restrict__ d, int n8){
  int i = blockIdx.x*256 + threadIdx.x;
  if (i >= n8) return;
  f32x4 a = *(const f32x4*)(s + (size_t)i*8);
  f32x4 b = *(const f32x4*)(s + (size_t)i*8 + 4);
  u16x8 u;
  #pragma unroll
  for (int r=0;r<4;r++){ u[r]=f2bf(a[r]); u[4+r]=f2bf(b[r]); }
  *(u16x8*)(d + (size_t)i*8) = u;
}

// ---------------- GEMM: C = A(bf16) @ W^T(bf16) + bias (m97 structure) ----------------
// OUTMODE 0: bf16 [b][h][s][hd]; OUTMODE 1: bf16 V^T [b][h][d][s]; OUTMODE 2: fp32 [m][n]
template<int OUTMODE>
__global__ __launch_bounds__(256) void gemm_bf16(
    const unsigned short* __restrict__ A, const unsigned short* __restrict__ Bw,
    const float* __restrict__ bias, void* __restrict__ Out, int m_base)
{
  __shared__ unsigned short Abuf[128*64];
  __shared__ unsigned short Bbuf[128*64];
  char* AbufB = (char*)Abuf; char* BbufB = (char*)Bbuf;
  const int tid  = threadIdx.x;
  const int lane = tid & 63, wid = tid >> 6;
  const int g = lane >> 4, l15 = lane & 15;
  const int wm = wid >> 1, wn = wid & 1;
  const int mt = blockIdx.x >> 4, nt = blockIdx.x & 15;
  const int mloc = mt*128, n0 = nt*128;
  const int srow = tid >> 3, slot = tid & 7;

  f32x4 acc[4][4];
  #pragma unroll
  for (int i=0;i<4;i++)
    #pragma unroll
    for (int j=0;j<4;j++) acc[i][j] = f32x4{0.f,0.f,0.f,0.f};

  for (int kt = 0; kt < ND; kt += 64) {
    #pragma unroll
    for (int c=0;c<4;c++){
      int row = c*32 + srow;
      int ss  = slot ^ (row & 7);
      gload16(Bw + (size_t)(n0+row)*ND + kt + ss*8, BbufB + c*4096 + tid*16);
      gload16(A  + (size_t)(mloc+row)*ND + kt + ss*8, AbufB + c*4096 + tid*16);
    }
    __syncthreads();
    #pragma unroll
    for (int kk=0;kk<2;kk++){
      s16x8 av[4], bv[4];
      #pragma unroll
      for (int i=0;i<4;i++){
        int r = wm*64 + i*16 + l15;
        av[i] = *(const s16x8*)(AbufB + r*128 + (((kk*4+g) ^ (r&7))*16));
      }
      #pragma unroll
      for (int j=0;j<4;j++){
        int r = wn*64 + j*16 + l15;
        bv[j] = *(const s16x8*)(BbufB + r*128 + (((kk*4+g) ^ (r&7))*16));
      }
      #pragma unroll
      for (int i=0;i<4;i++)
        #pragma unroll
        for (int j=0;j<4;j++)
          acc[i][j] = __builtin_amdgcn_mfma_f32_16x16x32_bf16(av[i], bv[j], acc[i][j], 0,0,0);
    }
    __syncthreads();
  }
  #pragma unroll
  for (int j=0;j<4;j++){
    int n = n0 + wn*64 + j*16 + l15;
    float bj = bias[n];
    #pragma unroll
    for (int i=0;i<4;i++){
      int mb = m_base + mloc + wm*64 + i*16 + g*4;
      if (OUTMODE == 2){
        float* O = (float*)Out;
        #pragma unroll
        for (int r=0;r<4;r++) O[(size_t)(mb+r)*ND + n] = acc[i][j][r] + bj;
      } else if (OUTMODE == 0){
        unsigned short* O = (unsigned short*)Out;
        int bb = mb >> 8, h = n >> 7, d = n & 127, s0 = mb & 255;
        #pragma unroll
        for (int r=0;r<4;r++)
          O[(((size_t)bb*NH + h)*NS + s0 + r)*NHD + d] = f2bf(acc[i][j][r] + bj);
      } else {
        unsigned short* O = (unsigned short*)Out;
        int bb = mb >> 8, h = n >> 7, d = n & 127, s0 = mb & 255;
        u16x4 u;
        #pragma unroll
        for (int r=0;r<4;r++) u[r] = f2bf(acc[i][j][r] + bj);
        *(u16x4*)(O + (((size_t)bb*NH + h)*NHD + d)*NS + s0) = u;
      }
    }
  }
}

// ---------------- fused attention: QK^T + bias/mask + softmax + PV ----------------
// One block per (bh, 64-q tile). 4 waves x 16 q-rows each.
// K[256][128] staged in LDS (64KB, XOR-swizzled), then V^T[128][256] re-staged
// into the same buffer. P (normalized, bf16) goes through a 32KB swizzled LDS
// buffer (wave-private region) to reformat lane layout for the PV B-fragment.
__global__ __launch_bounds__(256) void attn_fused_kernel(
  const unsigned short* __restrict__ Qh, const unsigned short* __restrict__ Kh,
  const unsigned short* __restrict__ VT, const int* __restrict__ mask,
  const float* __restrict__ bias_table, unsigned short* __restrict__ AO)
{
  __shared__ unsigned short KV[256*128];     // 64 KB: K tile, later V^T tile
  __shared__ unsigned short Plds[4*16*256];  // 32 KB: per-wave P scratch
  char* KVb = (char*)KV;
  const int bh = blockIdx.x >> 2, qt = blockIdx.x & 3;
  const int b = bh >> 4, h = bh & 15;
  const int tid = threadIdx.x;
  const int lane = tid & 63, wid = tid >> 6;
  const int g = lane >> 4, l15 = lane & 15;
  const int q = qt*64 + wid*16 + l15;

  // ---- stage K tile (rows of 128 bf16 = 16 slots of 16B, source pre-swizzled)
  {
    const unsigned short* Kb = Kh + (size_t)bh*NS*NHD;
    int srow = tid >> 4, slot = tid & 15;
    #pragma unroll
    for (int c=0;c<16;c++){
      int row = c*16 + srow;
      int ss  = slot ^ (row & 7);
      gload16(Kb + (size_t)row*NHD + ss*8, KVb + c*4096 + tid*16);
    }
  }
  // ---- Q row into regs
  const unsigned short* Qrow = Qh + ((size_t)bh*NS + q)*NHD;
  s16x8 bq[4];
  #pragma unroll
  for (int kk=0;kk<4;kk++) bq[kk] = *(const s16x8*)(Qrow + kk*32 + g*8);

  __syncthreads();   // drains vmcnt (global_load_lds) per barrier semantics

  // ---- QK^T from LDS: C[row=k, col=q]
  f32x4 c[16];
  #pragma unroll
  for (int kb=0;kb<16;kb++){
    c[kb] = f32x4{0.f,0.f,0.f,0.f};
    int row = kb*16 + l15;
    #pragma unroll
    for (int kk=0;kk<4;kk++){
      s16x8 a = *(const s16x8*)(KVb + row*256 + (((kk*4+g) ^ (row&7))*16));
      c[kb] = __builtin_amdgcn_mfma_f32_16x16x32_bf16(a, bq[kk], c[kb], 0,0,0);
    }
  }

  // ---- bias + mask + softmax (identical math to round 3)
  const float scale = 0.08838834764831845f; // 1/sqrt(128)
  const float* brow = bias_table + ((size_t)h*NS + q)*NS;
  const int*   mrow = mask + b*NS;
  float mx = -3.0e38f;
  #pragma unroll
  for (int kb=0;kb<16;kb++){
    f32x4 b4 = *(const f32x4*)(brow + kb*16 + g*4);
    i32x4 m4 = *(const i32x4*)(mrow + kb*16 + g*4);
    #pragma unroll
    for (int r=0;r<4;r++){
      float val = (m4[r] != 0) ? (c[kb][r]*scale + b4[r]) : -3.0e38f;
      c[kb][r] = val;
      mx = fmaxf(mx, val);
    }
  }
  mx = fmaxf(mx, __shfl_xor(mx, 16));
  mx = fmaxf(mx, __shfl_xor(mx, 32));
  float sum = 0.f;
  #pragma unroll
  for (int kb=0;kb<16;kb++)
    #pragma unroll
    for (int r=0;r<4;r++){
      float p = __expf(c[kb][r] - mx);
      c[kb][r] = p; sum += p;
    }
  sum += __shfl_xor(sum, 16);
  sum += __shfl_xor(sum, 32);
  float inv = 1.f / sum;

  // ---- write P (bf16) to wave-private LDS region, swizzled 16B slots
  {
    char* Pw = (char*)Plds + wid*8192;
    #pragma unroll
    for (int kb=0;kb<16;kb++){
      u16x4 u;
      #pragma unroll
      for (int r=0;r<4;r++) u[r] = f2bf(c[kb][r] * inv);
      *(u16x4*)(Pw + l15*512 + (((2*kb + (g>>1)) ^ (l15&7))*16) + (g&1)*8) = u;
    }
  }

  __syncthreads();   // all waves done reading K

  // ---- re-stage V^T tile [128][256] into KV (rows of 256 bf16 = 32 slots)
  {
    const unsigned short* Vb = VT + (size_t)bh*NHD*NS;
    int srow = tid >> 5, slot = tid & 31;
    #pragma unroll
    for (int c=0;c<16;c++){
      int row = c*8 + srow;
      int ss  = slot ^ (row & 7);
      gload16(Vb + (size_t)row*NS + ss*8, KVb + c*4096 + tid*16);
    }
  }
  __syncthreads();   // drains vmcnt; V visible to all waves

  // ---- PV: O[d][q] = sum_k V^T[d][k] * P[q][k]
  const char* Pr = (const char*)Plds + wid*8192;
  #pragma unroll
  for (int dt=0;dt<8;dt++){
    f32x4 acc = f32x4{0.f,0.f,0.f,0.f};
    int row = dt*16 + l15;
    #pragma unroll
    for (int kk=0;kk<8;kk++){
      s16x8 a  = *(const s16x8*)(KVb + row*512 + (((kk*4+g) ^ (row&7))*16));
      s16x8 pb = *(const s16x8*)(Pr  + l15*512 + (((kk*4+g) ^ (l15&7))*16));
      acc = __builtin_amdgcn_mfma_f32_16x16x32_bf16(a, pb, acc, 0,0,0);
    }
    u16x4 u;
    #pragma unroll
    for (int r=0;r<4;r++) u[r] = f2bf(acc[r]);
    *(u16x4*)(AO + ((size_t)b*NS + q)*ND + h*NHD + dt*16 + g*4) = u;
  }
}

extern "C" void kernel_launch(void* const* d_in, const int* in_sizes, int n_in,
                              void* d_out, int out_size, void* d_ws, size_t ws_size,
                              hipStream_t stream)
{
  const float* q  = (const float*)d_in[0];
  const float* k  = (const float*)d_in[1];
  const float* v  = (const float*)d_in[2];
  const int* mask = (const int*)d_in[3];
  const float* Wq = (const float*)d_in[4];
  const float* bq = (const float*)d_in[5];
  const float* Wk = (const float*)d_in[6];
  const float* bk = (const float*)d_in[7];
  const float* Wv = (const float*)d_in[8];
  const float* bv = (const float*)d_in[9];
  const float* Wo = (const float*)d_in[10];
  const float* bo = (const float*)d_in[11];
  const float* bias_table = (const float*)d_in[12];

  // workspace layout, max byte touched = 304 MiB (< 352 MiB proven in r1/r3):
  //   Wob [0,8M)   wb [8M,16M)   tmp [16M,48M)  (half-M chunk, 8192x2048 bf16)
  //   Qh [48M,112M)  Kh [112M,176M)  VT [176M,240M)  AO [240M,304M)
  //   NOTE: AO must NOT alias Qh — fused kernel reads Qh while writing AO
  //   (different index permutations of the same b-range -> cross-block race).
  char* ws = (char*)d_ws;
  unsigned short* Wob = (unsigned short*)(ws + 0);
  unsigned short* wb  = (unsigned short*)(ws + 8388608);
  unsigned short* tmp = (unsigned short*)(ws + 16777216);
  unsigned short* Qh  = (unsigned short*)(ws + 50331648);
  unsigned short* Kh  = (unsigned short*)(ws + 117440512);
  unsigned short* VT  = (unsigned short*)(ws + 184549376);
  unsigned short* AO  = (unsigned short*)(ws + 251658240);

  wconv<<<2048,256,0,stream>>>(Wo, Wob, 524288);

  const float* acts[3]  = {q, k, v};
  const float* wgt[3]   = {Wq, Wk, Wv};
  const float* bia[3]   = {bq, bk, bv};
  unsigned short* outs[3] = {Qh, Kh, VT};

  for (int x = 0; x < 3; ++x) {
    wconv<<<2048,256,0,stream>>>(wgt[x], wb, 524288);
    for (int hhalf = 0; hhalf < 2; ++hhalf) {
      const float* src = acts[x] + (size_t)hhalf*8192*ND;
      wconv<<<8192,256,0,stream>>>(src, tmp, 2097152);
      if (x < 2)
        gemm_bf16<0><<<1024,256,0,stream>>>(tmp, wb, bia[x], outs[x], hhalf*8192);
      else
        gemm_bf16<1><<<1024,256,0,stream>>>(tmp, wb, bia[x], outs[x], hhalf*8192);
    }
  }

  attn_fused_kernel<<<4096,256,0,stream>>>(Qh,Kh,VT,mask,bias_table,AO);
  gemm_bf16<2><<<2048,256,0,stream>>>(AO,Wob,bo,(float*)d_out,0);
}

// Round 5
// 842.222 us; speedup vs baseline: 1.4926x; 1.1741x over previous
//
#include <hip/hip_runtime.h>
#include <hip/hip_bf16.h>

typedef __attribute__((ext_vector_type(4))) float f32x4;
typedef __attribute__((ext_vector_type(8))) short s16x8;
typedef __attribute__((ext_vector_type(4))) unsigned short u16x4;
typedef __attribute__((ext_vector_type(8))) unsigned short u16x8;
typedef __attribute__((ext_vector_type(4))) int i32x4;

#define NB 64
#define NS 256
#define ND 2048
#define NH 16
#define NHD 128

__device__ __forceinline__ unsigned short f2bf(float f){
  unsigned int u = __float_as_uint(f);
  u += 0x7fffu + ((u >> 16) & 1u);
  return (unsigned short)(u >> 16);
}

__device__ __forceinline__ void gload16(const void* g, void* l){
  __builtin_amdgcn_global_load_lds(
    (const __attribute__((address_space(1))) unsigned int*)g,
    (__attribute__((address_space(3))) unsigned int*)l, 16, 0, 0);
}

#define SBAR()  __builtin_amdgcn_sched_barrier(0)
#define BARRIER() do{ SBAR(); __builtin_amdgcn_s_barrier(); SBAR(); }while(0)
#define WAIT_LGKM0() do{ asm volatile("s_waitcnt lgkmcnt(0)" ::: "memory"); SBAR(); }while(0)
#define WAIT_VM0()   do{ asm volatile("s_waitcnt vmcnt(0)"   ::: "memory"); SBAR(); }while(0)

// ---------------- fp32 -> bf16 conversion ----------------
__global__ __launch_bounds__(256) void wconv(const float* __restrict__ s,
                                             unsigned short* __restrict__ d, int n8){
  int i = blockIdx.x*256 + threadIdx.x;
  if (i >= n8) return;
  f32x4 a = *(const f32x4*)(s + (size_t)i*8);
  f32x4 b = *(const f32x4*)(s + (size_t)i*8 + 4);
  u16x8 u;
  #pragma unroll
  for (int r=0;r<4;r++){ u[r]=f2bf(a[r]); u[4+r]=f2bf(b[r]); }
  *(u16x8*)(d + (size_t)i*8) = u;
}

// ---------------- 256x256 8-phase GEMM: C = A(bf16) @ W^T(bf16) + bias ----------------
// 8 waves (2M x 4N), BK=64, 2-K-tile LDS double buffer (128 KiB, dynamic).
// Phases 1-4 compute K-tile 2t (dbuf0) and stage tile 2t+1 -> dbuf1 (1 half/phase);
// phases 5-8 compute tile 2t+1 (dbuf1) and stage tile 2t+2 -> dbuf0.
// vmcnt(0) only at phases 4/8 (after MFMA); all other sync = raw s_barrier.
// OUTMODE 0: bf16 [b][h][s][hd]; OUTMODE 1: bf16 V^T [b][h][d][s]; OUTMODE 2: fp32 [m][n]
template<int OUTMODE>
__global__ __launch_bounds__(512, 2) void gemm256(
    const unsigned short* __restrict__ A, const unsigned short* __restrict__ Bw,
    const float* __restrict__ bias, void* __restrict__ Out, int m_base)
{
  extern __shared__ __attribute__((aligned(16))) char ldsb[];  // 131072 B
  const int tid  = threadIdx.x;
  const int lane = tid & 63, wid = tid >> 6;
  const int g = lane >> 4, l15 = lane & 15;
  const int wm = wid >> 2, wn = wid & 3;

  // XCD-aware swizzle (grid % 8 == 0 for all callers)
  const int nwg = gridDim.x, bid = blockIdx.x;
  const int swz = (bid & 7) * (nwg >> 3) + (bid >> 3);
  const int mt = swz >> 3, nt = swz & 7;      // N = 2048 -> 8 n-tiles
  const int m0 = mt*256, n0 = nt*256;

  // staging bases: thread covers (half h, chunk c): row = h*128 + c*64 + (tid>>3),
  // 16B group = (tid&7) ^ (row&7)  (inverse swizzle on SOURCE, linear LDS dest)
  const int srow_l = tid >> 3;                      // 0..63
  const int scol   = (((tid & 7) ^ (srow_l & 7)) * 8);
  const unsigned short* gsrc[4];
  gsrc[0] = A  + (size_t)(m0 +       srow_l)*ND + scol;   // A half0
  gsrc[1] = A  + (size_t)(m0 + 128 + srow_l)*ND + scol;   // A half1
  gsrc[2] = Bw + (size_t)(n0 +       srow_l)*ND + scol;   // B half0
  gsrc[3] = Bw + (size_t)(n0 + 128 + srow_l)*ND + scol;   // B half1

#define STAGE(buf, p, kt) do{ \
    const unsigned short* s_ = gsrc[p] + (kt); \
    char* d_ = ldsb + (buf)*65536 + ((p)>>1)*32768 + ((p)&1)*16384 + tid*16; \
    gload16(s_, d_); gload16(s_ + (size_t)64*ND, d_ + 8192); }while(0)

#define RD_A(buf, qa) do{ \
    _Pragma("unroll") for (int i_=0;i_<4;i_++){ \
      int hr = (qa)*64 + i_*16 + l15; \
      const char* p_ = ldsb + (buf)*65536 + wm*16384 + hr*128; \
      _Pragma("unroll") for (int ks_=0;ks_<2;ks_++) \
        av[i_][ks_] = *(const s16x8*)(p_ + (((ks_*4+g) ^ (hr&7))*16)); } }while(0)

#define RD_B(buf, dst, qb) do{ \
    _Pragma("unroll") for (int j_=0;j_<2;j_++){ \
      int hc = (wn&1)*64 + (qb)*32 + j_*16 + l15; \
      const char* p_ = ldsb + (buf)*65536 + 32768 + (wn>>1)*16384 + hc*128; \
      _Pragma("unroll") for (int ks_=0;ks_<2;ks_++) \
        dst[j_][ks_] = *(const s16x8*)(p_ + (((ks_*4+g) ^ (hc&7))*16)); } }while(0)

#define MFMA_PH(qa, qb, bv) do{ \
    __builtin_amdgcn_s_setprio(1); \
    _Pragma("unroll") for (int i_=0;i_<4;i_++) \
      _Pragma("unroll") for (int j_=0;j_<2;j_++) \
        _Pragma("unroll") for (int ks_=0;ks_<2;ks_++) \
          acc[(qa)*4+i_][(qb)*2+j_] = __builtin_amdgcn_mfma_f32_16x16x32_bf16( \
              av[i_][ks_], bv[j_][ks_], acc[(qa)*4+i_][(qb)*2+j_], 0,0,0); \
    __builtin_amdgcn_s_setprio(0); }while(0)

  f32x4 acc[8][4];
  s16x8 av[4][2], bva[2][2], bvb[2][2];

  // prologue: stage K-tile 0 -> dbuf0
  STAGE(0,0,0); STAGE(0,1,0); STAGE(0,2,0); STAGE(0,3,0);
  #pragma unroll
  for (int i=0;i<8;i++)
    #pragma unroll
    for (int j=0;j<4;j++) acc[i][j] = f32x4{0.f,0.f,0.f,0.f};
  WAIT_VM0();
  BARRIER();

  for (int t = 0; t < 16; ++t) {
    const int kt1 = t*128 + 64, kt2 = t*128 + 128;
    // ---- phase 1 (qa0,qb0): read av(0)+bva; stage A0(2t+1)->dbuf1
    RD_A(0,0); RD_B(0,bva,0);
    STAGE(1,0,kt1);
    BARRIER(); WAIT_LGKM0();
    MFMA_PH(0,0,bva);
    BARRIER();
    // ---- phase 2 (qa0,qb1): read bvb; stage A1
    RD_B(0,bvb,1);
    STAGE(1,1,kt1);
    BARRIER(); WAIT_LGKM0();
    MFMA_PH(0,1,bvb);
    BARRIER();
    // ---- phase 3 (qa1,qb0): read av(1); stage B0
    RD_A(0,1);
    STAGE(1,2,kt1);
    BARRIER(); WAIT_LGKM0();
    MFMA_PH(1,0,bva);
    BARRIER();
    // ---- phase 4 (qa1,qb1): stage B1; MFMA; drain vmcnt
    STAGE(1,3,kt1);
    BARRIER(); WAIT_LGKM0();
    MFMA_PH(1,1,bvb);
    WAIT_VM0();
    BARRIER();
    // ---- phases 5-8: K-tile 2t+1 from dbuf1; stage tile 2t+2 -> dbuf0
    RD_A(1,0); RD_B(1,bva,0);
    if (t < 15) STAGE(0,0,kt2);
    BARRIER(); WAIT_LGKM0();
    MFMA_PH(0,0,bva);
    BARRIER();
    RD_B(1,bvb,1);
    if (t < 15) STAGE(0,1,kt2);
    BARRIER(); WAIT_LGKM0();
    MFMA_PH(0,1,bvb);
    BARRIER();
    RD_A(1,1);
    if (t < 15) STAGE(0,2,kt2);
    BARRIER(); WAIT_LGKM0();
    MFMA_PH(1,0,bva);
    BARRIER();
    if (t < 15) STAGE(0,3,kt2);
    BARRIER(); WAIT_LGKM0();
    MFMA_PH(1,1,bvb);
    WAIT_VM0();
    BARRIER();
  }

  // epilogue: wave strip = rows [wm*128,+128) x cols [wn*64,+64)
  #pragma unroll
  for (int jx=0;jx<4;jx++){
    int n = n0 + wn*64 + ((jx>>1)<<5) + ((jx&1)<<4) + l15;
    float bj = bias[n];
    #pragma unroll
    for (int i=0;i<8;i++){
      int mb = m_base + m0 + wm*128 + ((i>>2)<<6) + ((i&3)<<4) + g*4;
      if (OUTMODE == 2){
        float* O = (float*)Out;
        #pragma unroll
        for (int r=0;r<4;r++) O[(size_t)(mb+r)*ND + n] = acc[i][jx][r] + bj;
      } else if (OUTMODE == 0){
        unsigned short* O = (unsigned short*)Out;
        int bb = mb >> 8, h = n >> 7, d = n & 127, s0 = mb & 255;
        #pragma unroll
        for (int r=0;r<4;r++)
          O[(((size_t)bb*NH + h)*NS + s0 + r)*NHD + d] = f2bf(acc[i][jx][r] + bj);
      } else {
        unsigned short* O = (unsigned short*)Out;
        int bb = mb >> 8, h = n >> 7, d = n & 127, s0 = mb & 255;
        u16x4 u;
        #pragma unroll
        for (int r=0;r<4;r++) u[r] = f2bf(acc[i][jx][r] + bj);
        *(u16x4*)(O + (((size_t)bb*NH + h)*NHD + d)*NS + s0) = u;
      }
    }
  }
#undef STAGE
#undef RD_A
#undef RD_B
#undef MFMA_PH
}

// ---------------- fused attention (unchanged from round 4) ----------------
__global__ __launch_bounds__(256) void attn_fused_kernel(
  const unsigned short* __restrict__ Qh, const unsigned short* __restrict__ Kh,
  const unsigned short* __restrict__ VT, const int* __restrict__ mask,
  const float* __restrict__ bias_table, unsigned short* __restrict__ AO)
{
  __shared__ unsigned short KV[256*128];
  __shared__ unsigned short Plds[4*16*256];
  char* KVb = (char*)KV;
  const int bh = blockIdx.x >> 2, qt = blockIdx.x & 3;
  const int b = bh >> 4, h = bh & 15;
  const int tid = threadIdx.x;
  const int lane = tid & 63, wid = tid >> 6;
  const int g = lane >> 4, l15 = lane & 15;
  const int q = qt*64 + wid*16 + l15;

  {
    const unsigned short* Kb = Kh + (size_t)bh*NS*NHD;
    int srow = tid >> 4, slot = tid & 15;
    #pragma unroll
    for (int c=0;c<16;c++){
      int row = c*16 + srow;
      int ss  = slot ^ (row & 7);
      gload16(Kb + (size_t)row*NHD + ss*8, KVb + c*4096 + tid*16);
    }
  }
  const unsigned short* Qrow = Qh + ((size_t)bh*NS + q)*NHD;
  s16x8 bq[4];
  #pragma unroll
  for (int kk=0;kk<4;kk++) bq[kk] = *(const s16x8*)(Qrow + kk*32 + g*8);

  __syncthreads();

  f32x4 c[16];
  #pragma unroll
  for (int kb=0;kb<16;kb++){
    c[kb] = f32x4{0.f,0.f,0.f,0.f};
    int row = kb*16 + l15;
    #pragma unroll
    for (int kk=0;kk<4;kk++){
      s16x8 a = *(const s16x8*)(KVb + row*256 + (((kk*4+g) ^ (row&7))*16));
      c[kb] = __builtin_amdgcn_mfma_f32_16x16x32_bf16(a, bq[kk], c[kb], 0,0,0);
    }
  }

  const float scale = 0.08838834764831845f;
  const float* brow = bias_table + ((size_t)h*NS + q)*NS;
  const int*   mrow = mask + b*NS;
  float mx = -3.0e38f;
  #pragma unroll
  for (int kb=0;kb<16;kb++){
    f32x4 b4 = *(const f32x4*)(brow + kb*16 + g*4);
    i32x4 m4 = *(const i32x4*)(mrow + kb*16 + g*4);
    #pragma unroll
    for (int r=0;r<4;r++){
      float val = (m4[r] != 0) ? (c[kb][r]*scale + b4[r]) : -3.0e38f;
      c[kb][r] = val;
      mx = fmaxf(mx, val);
    }
  }
  mx = fmaxf(mx, __shfl_xor(mx, 16));
  mx = fmaxf(mx, __shfl_xor(mx, 32));
  float sum = 0.f;
  #pragma unroll
  for (int kb=0;kb<16;kb++)
    #pragma unroll
    for (int r=0;r<4;r++){
      float p = __expf(c[kb][r] - mx);
      c[kb][r] = p; sum += p;
    }
  sum += __shfl_xor(sum, 16);
  sum += __shfl_xor(sum, 32);
  float inv = 1.f / sum;

  {
    char* Pw = (char*)Plds + wid*8192;
    #pragma unroll
    for (int kb=0;kb<16;kb++){
      u16x4 u;
      #pragma unroll
      for (int r=0;r<4;r++) u[r] = f2bf(c[kb][r] * inv);
      *(u16x4*)(Pw + l15*512 + (((2*kb + (g>>1)) ^ (l15&7))*16) + (g&1)*8) = u;
    }
  }

  __syncthreads();

  {
    const unsigned short* Vb = VT + (size_t)bh*NHD*NS;
    int srow = tid >> 5, slot = tid & 31;
    #pragma unroll
    for (int c2=0;c2<16;c2++){
      int row = c2*8 + srow;
      int ss  = slot ^ (row & 7);
      gload16(Vb + (size_t)row*NS + ss*8, KVb + c2*4096 + tid*16);
    }
  }
  __syncthreads();

  const char* Pr = (const char*)Plds + wid*8192;
  #pragma unroll
  for (int dt=0;dt<8;dt++){
    f32x4 acc = f32x4{0.f,0.f,0.f,0.f};
    int row = dt*16 + l15;
    #pragma unroll
    for (int kk=0;kk<8;kk++){
      s16x8 a  = *(const s16x8*)(KVb + row*512 + (((kk*4+g) ^ (row&7))*16));
      s16x8 pb = *(const s16x8*)(Pr  + l15*512 + (((kk*4+g) ^ (l15&7))*16));
      acc = __builtin_amdgcn_mfma_f32_16x16x32_bf16(a, pb, acc, 0,0,0);
    }
    u16x4 u;
    #pragma unroll
    for (int r=0;r<4;r++) u[r] = f2bf(acc[r]);
    *(u16x4*)(AO + ((size_t)b*NS + q)*ND + h*NHD + dt*16 + g*4) = u;
  }
}

extern "C" void kernel_launch(void* const* d_in, const int* in_sizes, int n_in,
                              void* d_out, int out_size, void* d_ws, size_t ws_size,
                              hipStream_t stream)
{
  const float* q  = (const float*)d_in[0];
  const float* k  = (const float*)d_in[1];
  const float* v  = (const float*)d_in[2];
  const int* mask = (const int*)d_in[3];
  const float* Wq = (const float*)d_in[4];
  const float* bq = (const float*)d_in[5];
  const float* Wk = (const float*)d_in[6];
  const float* bk = (const float*)d_in[7];
  const float* Wv = (const float*)d_in[8];
  const float* bv = (const float*)d_in[9];
  const float* Wo = (const float*)d_in[10];
  const float* bo = (const float*)d_in[11];
  const float* bias_table = (const float*)d_in[12];

  // workspace layout (max 304 MiB, proven):
  //   Wob [0,8M)  wb [8M,16M)  tmp [16M,48M)  Qh [48M,112M)
  //   Kh [112M,176M)  VT [176M,240M)  AO [240M,304M)  (AO must not alias Qh)
  char* ws = (char*)d_ws;
  unsigned short* Wob = (unsigned short*)(ws + 0);
  unsigned short* wb  = (unsigned short*)(ws + 8388608);
  unsigned short* tmp = (unsigned short*)(ws + 16777216);
  unsigned short* Qh  = (unsigned short*)(ws + 50331648);
  unsigned short* Kh  = (unsigned short*)(ws + 117440512);
  unsigned short* VT  = (unsigned short*)(ws + 184549376);
  unsigned short* AO  = (unsigned short*)(ws + 251658240);

  hipFuncSetAttribute((const void*)gemm256<0>, hipFuncAttributeMaxDynamicSharedMemorySize, 131072);
  hipFuncSetAttribute((const void*)gemm256<1>, hipFuncAttributeMaxDynamicSharedMemorySize, 131072);
  hipFuncSetAttribute((const void*)gemm256<2>, hipFuncAttributeMaxDynamicSharedMemorySize, 131072);

  wconv<<<2048,256,0,stream>>>(Wo, Wob, 524288);

  const float* acts[3]  = {q, k, v};
  const float* wgt[3]   = {Wq, Wk, Wv};
  const float* bia[3]   = {bq, bk, bv};
  unsigned short* outs[3] = {Qh, Kh, VT};

  for (int x = 0; x < 3; ++x) {
    wconv<<<2048,256,0,stream>>>(wgt[x], wb, 524288);
    for (int hhalf = 0; hhalf < 2; ++hhalf) {
      const float* src = acts[x] + (size_t)hhalf*8192*ND;
      wconv<<<8192,256,0,stream>>>(src, tmp, 2097152);
      if (x < 2)
        gemm256<0><<<256,512,131072,stream>>>(tmp, wb, bia[x], outs[x], hhalf*8192);
      else
        gemm256<1><<<256,512,131072,stream>>>(tmp, wb, bia[x], outs[x], hhalf*8192);
    }
  }

  attn_fused_kernel<<<4096,256,0,stream>>>(Qh,Kh,VT,mask,bias_table,AO);
  gemm256<2><<<512,512,131072,stream>>>(AO,Wob,bo,(float*)d_out,0);
}

// Round 6
// 779.062 us; speedup vs baseline: 1.6136x; 1.0811x over previous
//
#include <hip/hip_runtime.h>
#include <hip/hip_bf16.h>

typedef __attribute__((ext_vector_type(4))) float f32x4;
typedef __attribute__((ext_vector_type(8))) short s16x8;
typedef __attribute__((ext_vector_type(4))) unsigned short u16x4;
typedef __attribute__((ext_vector_type(8))) unsigned short u16x8;
typedef __attribute__((ext_vector_type(4))) int i32x4;

#define NB 64
#define NS 256
#define ND 2048
#define NH 16
#define NHD 128

__device__ __forceinline__ unsigned short f2bf(float f){
  unsigned int u = __float_as_uint(f);
  u += 0x7fffu + ((u >> 16) & 1u);
  return (unsigned short)(u >> 16);
}

__device__ __forceinline__ void gload16(const void* g, void* l){
  __builtin_amdgcn_global_load_lds(
    (const __attribute__((address_space(1))) unsigned int*)g,
    (__attribute__((address_space(3))) unsigned int*)l, 16, 0, 0);
}

#define SBAR()  __builtin_amdgcn_sched_barrier(0)
#define BARRIER() do{ SBAR(); __builtin_amdgcn_s_barrier(); SBAR(); }while(0)
#define WAIT_LGKM0() do{ asm volatile("s_waitcnt lgkmcnt(0)" ::: "memory"); SBAR(); }while(0)
#define WAIT_VM0()   do{ asm volatile("s_waitcnt vmcnt(0)"   ::: "memory"); SBAR(); }while(0)
#define WAIT_VM8()   do{ asm volatile("s_waitcnt vmcnt(8)"   ::: "memory"); SBAR(); }while(0)

// ---------------- fp32 -> bf16 conversion ----------------
__global__ __launch_bounds__(256) void wconv(const float* __restrict__ s,
                                             unsigned short* __restrict__ d, int n8){
  int i = blockIdx.x*256 + threadIdx.x;
  if (i >= n8) return;
  f32x4 a = *(const f32x4*)(s + (size_t)i*8);
  f32x4 b = *(const f32x4*)(s + (size_t)i*8 + 4);
  u16x8 u;
  #pragma unroll
  for (int r=0;r<4;r++){ u[r]=f2bf(a[r]); u[4+r]=f2bf(b[r]); }
  *(u16x8*)(d + (size_t)i*8) = u;
}

// ---------------- 256x256 8-phase GEMM (unchanged from round 5) ----------------
template<int OUTMODE>
__global__ __launch_bounds__(512, 2) void gemm256(
    const unsigned short* __restrict__ A, const unsigned short* __restrict__ Bw,
    const float* __restrict__ bias, void* __restrict__ Out, int m_base)
{
  extern __shared__ __attribute__((aligned(16))) char ldsb[];  // 131072 B
  const int tid  = threadIdx.x;
  const int lane = tid & 63, wid = tid >> 6;
  const int g = lane >> 4, l15 = lane & 15;
  const int wm = wid >> 2, wn = wid & 3;

  const int nwg = gridDim.x, bid = blockIdx.x;
  const int swz = (bid & 7) * (nwg >> 3) + (bid >> 3);
  const int mt = swz >> 3, nt = swz & 7;
  const int m0 = mt*256, n0 = nt*256;

  const int srow_l = tid >> 3;
  const int scol   = (((tid & 7) ^ (srow_l & 7)) * 8);
  const unsigned short* gsrc[4];
  gsrc[0] = A  + (size_t)(m0 +       srow_l)*ND + scol;
  gsrc[1] = A  + (size_t)(m0 + 128 + srow_l)*ND + scol;
  gsrc[2] = Bw + (size_t)(n0 +       srow_l)*ND + scol;
  gsrc[3] = Bw + (size_t)(n0 + 128 + srow_l)*ND + scol;

#define STAGE(buf, p, kt) do{ \
    const unsigned short* s_ = gsrc[p] + (kt); \
    char* d_ = ldsb + (buf)*65536 + ((p)>>1)*32768 + ((p)&1)*16384 + tid*16; \
    gload16(s_, d_); gload16(s_ + (size_t)64*ND, d_ + 8192); }while(0)

#define RD_A(buf, qa) do{ \
    _Pragma("unroll") for (int i_=0;i_<4;i_++){ \
      int hr = (qa)*64 + i_*16 + l15; \
      const char* p_ = ldsb + (buf)*65536 + wm*16384 + hr*128; \
      _Pragma("unroll") for (int ks_=0;ks_<2;ks_++) \
        av[i_][ks_] = *(const s16x8*)(p_ + (((ks_*4+g) ^ (hr&7))*16)); } }while(0)

#define RD_B(buf, dst, qb) do{ \
    _Pragma("unroll") for (int j_=0;j_<2;j_++){ \
      int hc = (wn&1)*64 + (qb)*32 + j_*16 + l15; \
      const char* p_ = ldsb + (buf)*65536 + 32768 + (wn>>1)*16384 + hc*128; \
      _Pragma("unroll") for (int ks_=0;ks_<2;ks_++) \
        dst[j_][ks_] = *(const s16x8*)(p_ + (((ks_*4+g) ^ (hc&7))*16)); } }while(0)

#define MFMA_PH(qa, qb, bv) do{ \
    __builtin_amdgcn_s_setprio(1); \
    _Pragma("unroll") for (int i_=0;i_<4;i_++) \
      _Pragma("unroll") for (int j_=0;j_<2;j_++) \
        _Pragma("unroll") for (int ks_=0;ks_<2;ks_++) \
          acc[(qa)*4+i_][(qb)*2+j_] = __builtin_amdgcn_mfma_f32_16x16x32_bf16( \
              av[i_][ks_], bv[j_][ks_], acc[(qa)*4+i_][(qb)*2+j_], 0,0,0); \
    __builtin_amdgcn_s_setprio(0); }while(0)

  f32x4 acc[8][4];
  s16x8 av[4][2], bva[2][2], bvb[2][2];

  STAGE(0,0,0); STAGE(0,1,0); STAGE(0,2,0); STAGE(0,3,0);
  #pragma unroll
  for (int i=0;i<8;i++)
    #pragma unroll
    for (int j=0;j<4;j++) acc[i][j] = f32x4{0.f,0.f,0.f,0.f};
  WAIT_VM0();
  BARRIER();

  for (int t = 0; t < 16; ++t) {
    const int kt1 = t*128 + 64, kt2 = t*128 + 128;
    RD_A(0,0); RD_B(0,bva,0);
    STAGE(1,0,kt1);
    BARRIER(); WAIT_LGKM0();
    MFMA_PH(0,0,bva);
    BARRIER();
    RD_B(0,bvb,1);
    STAGE(1,1,kt1);
    BARRIER(); WAIT_LGKM0();
    MFMA_PH(0,1,bvb);
    BARRIER();
    RD_A(0,1);
    STAGE(1,2,kt1);
    BARRIER(); WAIT_LGKM0();
    MFMA_PH(1,0,bva);
    BARRIER();
    STAGE(1,3,kt1);
    BARRIER(); WAIT_LGKM0();
    MFMA_PH(1,1,bvb);
    WAIT_VM0();
    BARRIER();
    RD_A(1,0); RD_B(1,bva,0);
    if (t < 15) STAGE(0,0,kt2);
    BARRIER(); WAIT_LGKM0();
    MFMA_PH(0,0,bva);
    BARRIER();
    RD_B(1,bvb,1);
    if (t < 15) STAGE(0,1,kt2);
    BARRIER(); WAIT_LGKM0();
    MFMA_PH(0,1,bvb);
    BARRIER();
    RD_A(1,1);
    if (t < 15) STAGE(0,2,kt2);
    BARRIER(); WAIT_LGKM0();
    MFMA_PH(1,0,bva);
    BARRIER();
    if (t < 15) STAGE(0,3,kt2);
    BARRIER(); WAIT_LGKM0();
    MFMA_PH(1,1,bvb);
    WAIT_VM0();
    BARRIER();
  }

  #pragma unroll
  for (int jx=0;jx<4;jx++){
    int n = n0 + wn*64 + ((jx>>1)<<5) + ((jx&1)<<4) + l15;
    float bj = bias[n];
    #pragma unroll
    for (int i=0;i<8;i++){
      int mb = m_base + m0 + wm*128 + ((i>>2)<<6) + ((i&3)<<4) + g*4;
      if (OUTMODE == 2){
        float* O = (float*)Out;
        #pragma unroll
        for (int r=0;r<4;r++) O[(size_t)(mb+r)*ND + n] = acc[i][jx][r] + bj;
      } else if (OUTMODE == 0){
        unsigned short* O = (unsigned short*)Out;
        int bb = mb >> 8, h = n >> 7, d = n & 127, s0 = mb & 255;
        #pragma unroll
        for (int r=0;r<4;r++)
          O[(((size_t)bb*NH + h)*NS + s0 + r)*NHD + d] = f2bf(acc[i][jx][r] + bj);
      } else {
        unsigned short* O = (unsigned short*)Out;
        int bb = mb >> 8, h = n >> 7, d = n & 127, s0 = mb & 255;
        u16x4 u;
        #pragma unroll
        for (int r=0;r<4;r++) u[r] = f2bf(acc[i][jx][r] + bj);
        *(u16x4*)(O + (((size_t)bb*NH + h)*NHD + d)*NS + s0) = u;
      }
    }
  }
#undef STAGE
#undef RD_A
#undef RD_B
#undef MFMA_PH
}

// ---------------- fused attention v2: one block per bh ----------------
// 512 thr / 8 waves; wave w owns q rows [w*32, w*32+32) as 2 passes of 16.
// K[256][128] + V^T[128][256] both staged to LDS up front (128 KB).
// vmcnt(8) -> barrier lets QKT start while V loads are still in flight;
// single vmcnt(0)+barrier before pass-0 PV. P never touches LDS: the PV
// B-fragment is built by an in-register 4-lane shuffle remap.
__global__ __launch_bounds__(512, 1) void attn_fused2(
  const unsigned short* __restrict__ Qh, const unsigned short* __restrict__ Kh,
  const unsigned short* __restrict__ VT, const int* __restrict__ mask,
  const float* __restrict__ bias_table, unsigned short* __restrict__ AO)
{
  __shared__ unsigned short Klds[256*128];   // 64 KB
  __shared__ unsigned short Vlds[128*256];   // 64 KB
  char* Kb_ = (char*)Klds; char* Vb_ = (char*)Vlds;
  const int bh = blockIdx.x, b = bh >> 4, h = bh & 15;
  const int tid = threadIdx.x, lane = tid & 63, w = tid >> 6;
  const int g = lane >> 4, l15 = lane & 15;

  // stage K (8 gload16/thread), rows of 256B = 16 slots
  {
    const unsigned short* Ksrc = Kh + (size_t)bh*NS*NHD;
    int r0 = tid >> 4, sl = tid & 15;
    #pragma unroll
    for (int c=0;c<8;c++){
      int row = c*32 + r0;
      gload16(Ksrc + (size_t)row*NHD + ((sl ^ (row&7))*8), Kb_ + c*8192 + tid*16);
    }
  }
  // stage V^T (8 gload16/thread), rows of 512B = 32 slots
  {
    const unsigned short* Vsrc = VT + (size_t)bh*NHD*NS;
    int r0 = tid >> 5, sl = tid & 31;
    #pragma unroll
    for (int c=0;c<8;c++){
      int row = c*16 + r0;
      gload16(Vsrc + (size_t)row*NS + ((sl ^ (row&7))*8), Vb_ + c*8192 + tid*16);
    }
  }
  WAIT_VM8();    // own K loads done (8 V still in flight)
  BARRIER();     // all waves' K loads done -> K tile valid

  const float scale = 0.08838834764831845f; // 1/sqrt(128)
  const int* mrow = mask + b*NS;
  const int s0l = l15 + ((g&1)<<5), s1l = s0l + 16;
  const int sel = g >> 1;

  auto pass = [&](int p, bool wait_v){
    const int q = w*32 + p*16 + l15;
    const unsigned short* Qrow = Qh + ((size_t)bh*NS + q)*NHD;
    s16x8 bq[4];
    #pragma unroll
    for (int kk=0;kk<4;kk++) bq[kk] = *(const s16x8*)(Qrow + kk*32 + g*8);

    // QK^T from LDS: lane holds S[k=kb*16+g*4+r][q=l15]
    f32x4 c[16];
    __builtin_amdgcn_s_setprio(1);
    #pragma unroll
    for (int kb=0;kb<16;kb++){
      c[kb] = f32x4{0.f,0.f,0.f,0.f};
      int row = kb*16 + l15;
      #pragma unroll
      for (int kk=0;kk<4;kk++){
        s16x8 a = *(const s16x8*)(Kb_ + row*256 + (((kk*4+g) ^ (row&7))*16));
        c[kb] = __builtin_amdgcn_mfma_f32_16x16x32_bf16(a, bq[kk], c[kb], 0,0,0);
      }
    }
    __builtin_amdgcn_s_setprio(0);

    // bias + mask + softmax (identical math to rounds 3-5)
    const float* brow = bias_table + ((size_t)h*NS + q)*NS;
    float mx = -3.0e38f;
    #pragma unroll
    for (int kb=0;kb<16;kb++){
      f32x4 b4 = *(const f32x4*)(brow + kb*16 + g*4);
      i32x4 m4 = *(const i32x4*)(mrow + kb*16 + g*4);
      #pragma unroll
      for (int r=0;r<4;r++){
        float val = (m4[r] != 0) ? (c[kb][r]*scale + b4[r]) : -3.0e38f;
        c[kb][r] = val;
        mx = fmaxf(mx, val);
      }
    }
    mx = fmaxf(mx, __shfl_xor(mx, 16));
    mx = fmaxf(mx, __shfl_xor(mx, 32));
    float sum = 0.f;
    #pragma unroll
    for (int kb=0;kb<16;kb++)
      #pragma unroll
      for (int r=0;r<4;r++){
        float pv = __expf(c[kb][r] - mx);
        c[kb][r] = pv; sum += pv;
      }
    sum += __shfl_xor(sum, 16);
    sum += __shfl_xor(sum, 32);
    float inv = 1.f / sum;

    // pack P to bf16 pairs: pk[kb] = {(r0,r1),(r2,r3)}
    unsigned int pk[16][2];
    #pragma unroll
    for (int kb=0;kb<16;kb++){
      pk[kb][0] = (unsigned int)f2bf(c[kb][0]*inv) | ((unsigned int)f2bf(c[kb][1]*inv) << 16);
      pk[kb][1] = (unsigned int)f2bf(c[kb][2]*inv) | ((unsigned int)f2bf(c[kb][3]*inv) << 16);
    }

    if (wait_v){ WAIT_VM0(); BARRIER(); }   // V tile now valid (once)

    // build PV B-fragments in-register: lane (l15,g) needs P[q=l15][kk*32+g*8+j]
    // sources: lanes l15+16*{2(g&1), 2(g&1)+1}, kb = 2kk + (g>>1)
    s16x8 pb[8];
    #pragma unroll
    for (int kk=0;kk<8;kk++){
      unsigned int e0 = (unsigned int)__shfl((int)pk[2*kk][0],   s0l);
      unsigned int e1 = (unsigned int)__shfl((int)pk[2*kk][1],   s0l);
      unsigned int e2 = (unsigned int)__shfl((int)pk[2*kk][0],   s1l);
      unsigned int e3 = (unsigned int)__shfl((int)pk[2*kk][1],   s1l);
      unsigned int o0 = (unsigned int)__shfl((int)pk[2*kk+1][0], s0l);
      unsigned int o1 = (unsigned int)__shfl((int)pk[2*kk+1][1], s0l);
      unsigned int o2 = (unsigned int)__shfl((int)pk[2*kk+1][0], s1l);
      unsigned int o3 = (unsigned int)__shfl((int)pk[2*kk+1][1], s1l);
      union { unsigned int wd[4]; s16x8 v; } u_;
      u_.wd[0] = sel ? o0 : e0; u_.wd[1] = sel ? o1 : e1;
      u_.wd[2] = sel ? o2 : e2; u_.wd[3] = sel ? o3 : e3;
      pb[kk] = u_.v;
    }

    // PV: O[d][q] = sum_k V^T[d][k] * P[q][k]
    f32x4 oacc[8];
    __builtin_amdgcn_s_setprio(1);
    #pragma unroll
    for (int dt=0;dt<8;dt++){
      oacc[dt] = f32x4{0.f,0.f,0.f,0.f};
      int row = dt*16 + l15;
      #pragma unroll
      for (int kk=0;kk<8;kk++){
        s16x8 a = *(const s16x8*)(Vb_ + row*512 + (((kk*4+g) ^ (row&7))*16));
        oacc[dt] = __builtin_amdgcn_mfma_f32_16x16x32_bf16(a, pb[kk], oacc[dt], 0,0,0);
      }
    }
    __builtin_amdgcn_s_setprio(0);

    // write: lane holds O[d=dt*16+g*4+r][q=l15]
    #pragma unroll
    for (int dt=0;dt<8;dt++){
      u16x4 u;
      #pragma unroll
      for (int r=0;r<4;r++) u[r] = f2bf(oacc[dt][r]);
      *(u16x4*)(AO + ((size_t)b*NS + q)*ND + h*NHD + dt*16 + g*4) = u;
    }
  };

  pass(0, true);
  pass(1, false);
}

extern "C" void kernel_launch(void* const* d_in, const int* in_sizes, int n_in,
                              void* d_out, int out_size, void* d_ws, size_t ws_size,
                              hipStream_t stream)
{
  const float* q  = (const float*)d_in[0];
  const float* k  = (const float*)d_in[1];
  const float* v  = (const float*)d_in[2];
  const int* mask = (const int*)d_in[3];
  const float* Wq = (const float*)d_in[4];
  const float* bq = (const float*)d_in[5];
  const float* Wk = (const float*)d_in[6];
  const float* bk = (const float*)d_in[7];
  const float* Wv = (const float*)d_in[8];
  const float* bv = (const float*)d_in[9];
  const float* Wo = (const float*)d_in[10];
  const float* bo = (const float*)d_in[11];
  const float* bias_table = (const float*)d_in[12];

  // workspace layout, max 336 MiB (< proven 352 MiB):
  //   Wob [0,8M)  wb [8M,16M)  tmp [16M,80M) (full-M bf16 activations)
  //   Qh [80M,144M)  Kh [144M,208M)  VT [208M,272M)  AO [272M,336M)
  char* ws = (char*)d_ws;
  unsigned short* Wob = (unsigned short*)(ws + 0);
  unsigned short* wb  = (unsigned short*)(ws + 8388608);
  unsigned short* tmp = (unsigned short*)(ws + 16777216);
  unsigned short* Qh  = (unsigned short*)(ws + 83886080);
  unsigned short* Kh  = (unsigned short*)(ws + 150994944);
  unsigned short* VT  = (unsigned short*)(ws + 218103808);
  unsigned short* AO  = (unsigned short*)(ws + 285212672);

  hipFuncSetAttribute((const void*)gemm256<0>, hipFuncAttributeMaxDynamicSharedMemorySize, 131072);
  hipFuncSetAttribute((const void*)gemm256<1>, hipFuncAttributeMaxDynamicSharedMemorySize, 131072);
  hipFuncSetAttribute((const void*)gemm256<2>, hipFuncAttributeMaxDynamicSharedMemorySize, 131072);

  wconv<<<2048,256,0,stream>>>(Wo, Wob, 524288);

  const float* acts[3]  = {q, k, v};
  const float* wgt[3]   = {Wq, Wk, Wv};
  const float* bia[3]   = {bq, bk, bv};
  unsigned short* outs[3] = {Qh, Kh, VT};

  for (int x = 0; x < 3; ++x) {
    wconv<<<2048,256,0,stream>>>(wgt[x], wb, 524288);
    wconv<<<16384,256,0,stream>>>(acts[x], tmp, 4194304);
    if (x < 2)
      gemm256<0><<<512,512,131072,stream>>>(tmp, wb, bia[x], outs[x], 0);
    else
      gemm256<1><<<512,512,131072,stream>>>(tmp, wb, bia[x], outs[x], 0);
  }

  attn_fused2<<<1024,512,0,stream>>>(Qh,Kh,VT,mask,bias_table,AO);
  gemm256<2><<<512,512,131072,stream>>>(AO,Wob,bo,(float*)d_out,0);
}